// Round 3
// baseline (2095.367 us; speedup 1.0000x reference)
//
#include <hip/hip_runtime.h>

// FrozenBNBEmbedding: dequantize-blockwise int8->fp32 LUT + embedding gather.
// DIM == BLOCK == 4096 => one absmax scale per vocab row.
//
// V3: CALIBRATION PROBE (intentionally repeats work R=32 times).
// Purpose: (a) make the kernel dispatch the longest so rocprof's top-5 shows its
// counter row (FETCH/WRITE/bank-conflict/hbm_gbps); (b) recover the true
// single-pass kernel time K = total_base + dispatch_slow - total_slow, since the
// kernel is the only thing changed in the timed region.
// The asm memory fence per repeat defeats load-CSE and dead-store elimination
// (learn_hip rule #17) while keeping the output bit-identical.

#define DIM 4096
#define REPEAT 32

typedef float fx4 __attribute__((ext_vector_type(4)));

__global__ __launch_bounds__(256) void bnb_embed_kernel(
    const int* __restrict__ tokens,
    const int* __restrict__ weight,
    const float* __restrict__ absmax,
    const float* __restrict__ code,
    float* __restrict__ out,
    int n_tokens)
{
    __shared__ float lut[256];
    lut[threadIdx.x] = code[threadIdx.x];
    __syncthreads();

    const int wave = threadIdx.x >> 6;
    const int lane = threadIdx.x & 63;
    const int waveGlobal  = blockIdx.x * 4 + wave;
    const int nWavesTotal = gridDim.x * 4;

    for (int tok = waveGlobal; tok < n_tokens; tok += nWavesTotal) {
        const int   t     = __builtin_amdgcn_readfirstlane(tokens[tok]);
        const float scale = absmax[t];

        const int4* __restrict__ wrow = (const int4*)(weight + (size_t)t * DIM);
        fx4* __restrict__ orow        = (fx4*)(out + (size_t)tok * DIM);

#pragma unroll 1
        for (int r = 0; r < REPEAT; ++r) {
            // Fence: loads below cannot be CSE'd with the previous repeat's,
            // and the previous repeat's stores cannot be eliminated.
            asm volatile("" ::: "memory");

            int4 q[16];
#pragma unroll
            for (int i = 0; i < 16; ++i)
                q[i] = wrow[lane + i * 64];

#pragma unroll
            for (int i = 0; i < 16; ++i) {
                fx4 o;
                o.x = lut[q[i].x & 255] * scale;
                o.y = lut[q[i].y & 255] * scale;
                o.z = lut[q[i].z & 255] * scale;
                o.w = lut[q[i].w & 255] * scale;
                __builtin_nontemporal_store(o, &orow[lane + i * 64]);
            }
        }
    }
}

extern "C" void kernel_launch(void* const* d_in, const int* in_sizes, int n_in,
                              void* d_out, int out_size, void* d_ws, size_t ws_size,
                              hipStream_t stream)
{
    const int*   tokens = (const int*)d_in[0];
    const int*   weight = (const int*)d_in[1];
    const float* absmax = (const float*)d_in[2];
    const float* code   = (const float*)d_in[3];
    float*       out    = (float*)d_out;

    const int n_tokens = in_sizes[0];             // 8192

    int blocks = (n_tokens + 3) / 4;
    if (blocks > 2048) blocks = 2048;
    if (blocks < 1)    blocks = 1;

    bnb_embed_kernel<<<blocks, 256, 0, stream>>>(tokens, weight, absmax, code, out, n_tokens);
}

// Round 4
// 946.621 us; speedup vs baseline: 2.2135x; 2.2135x over previous
//
#include <hip/hip_runtime.h>

// FrozenBNBEmbedding: dequantize-blockwise (int8 codes -> fp32 via 256-entry LUT,
// per-4096-block absmax scale) fused with embedding gather.
// DIM == BLOCK == 4096  =>  one absmax scale per vocab row.
//
// V4 == V2.1 (revert of the REPEAT=32 calibration probe).
// Calibration (round 3) established:
//   single-pass kernel K ~= 37-39 us  (1239us/32 in-probe; (2095-941)/31 delta method)
//   = memory roofline: ~64 MB HBM fetch (L3 absorbs re-reads of ~120 MB unique rows)
//     + 134 MB NT writes ~= 198 MB @ ~5.1-6.3 TB/s -> 31-39 us.
//   VALUBusy 3.4%, bank-conflicts ~7% of LDS reads (hidden under VMEM).
// The remaining ~900 us of dur_us is harness poison-fill overhead (3.3 GB fills
// at ~80% HBM peak), not kernel-addressable.
//
// Structure: wave-per-token, 16 independent int4 loads in flight per wave,
// scalar token/absmax path, non-temporal float4 stores (write-once output,
// keeps weight rows L2/L3-resident).

#define DIM 4096

typedef float fx4 __attribute__((ext_vector_type(4)));

__global__ __launch_bounds__(256) void bnb_embed_kernel(
    const int* __restrict__ tokens,    // [n_tokens] token ids
    const int* __restrict__ weight,    // [VOCAB, DIM] int8 codes stored as int32
    const float* __restrict__ absmax,  // [VOCAB] per-row scale (n_blocks == VOCAB here)
    const float* __restrict__ code,    // [256] LUT
    float* __restrict__ out,           // [n_tokens, DIM] fp32
    int n_tokens)
{
    __shared__ float lut[256];
    lut[threadIdx.x] = code[threadIdx.x];
    __syncthreads();

    const int wave = threadIdx.x >> 6;   // 0..3
    const int lane = threadIdx.x & 63;
    const int waveGlobal  = blockIdx.x * 4 + wave;
    const int nWavesTotal = gridDim.x * 4;

    for (int tok = waveGlobal; tok < n_tokens; tok += nWavesTotal) {
        // Wave-uniform: force scalar path so the row-data VMEM queue stays clean.
        const int   t     = __builtin_amdgcn_readfirstlane(tokens[tok]);
        const float scale = absmax[t];

        const int4* __restrict__ wrow = (const int4*)(weight + (size_t)t * DIM);
        fx4* __restrict__ orow        = (fx4*)(out + (size_t)tok * DIM);

        // 4096 elems / 4-per-vec = 1024 int4; 64 lanes -> 16 int4 per lane.
        // Issue all 16 loads first: 16 KiB in flight per wave.
        int4 q[16];
#pragma unroll
        for (int i = 0; i < 16; ++i)
            q[i] = wrow[lane + i * 64];

#pragma unroll
        for (int i = 0; i < 16; ++i) {
            fx4 o;
            o.x = lut[q[i].x & 255] * scale;
            o.y = lut[q[i].y & 255] * scale;
            o.z = lut[q[i].z & 255] * scale;
            o.w = lut[q[i].w & 255] * scale;
            __builtin_nontemporal_store(o, &orow[lane + i * 64]);
        }
    }
}

extern "C" void kernel_launch(void* const* d_in, const int* in_sizes, int n_in,
                              void* d_out, int out_size, void* d_ws, size_t ws_size,
                              hipStream_t stream)
{
    const int*   tokens = (const int*)d_in[0];    // [4, 2048] int32
    const int*   weight = (const int*)d_in[1];    // [50400, 4096] int32
    const float* absmax = (const float*)d_in[2];  // [50400] fp32
    const float* code   = (const float*)d_in[3];  // [256] fp32
    float*       out    = (float*)d_out;          // [4, 2048, 4096] fp32

    const int n_tokens = in_sizes[0];             // 8192

    int blocks = (n_tokens + 3) / 4;              // one token per wave
    if (blocks > 2048) blocks = 2048;             // 2048*4 = 8192 waves; grid-stride covers rest
    if (blocks < 1)    blocks = 1;

    bnb_embed_kernel<<<blocks, 256, 0, stream>>>(tokens, weight, absmax, code, out, n_tokens);
}